// Round 1
// baseline (2843.217 us; speedup 1.0000x reference)
//
#include <hip/hip_runtime.h>
#include <cmath>

#define NN 4
#define CC 64
#define HH 256
#define WW 448
#define HW (HH * WW)          // 114688
#define CHW (CC * HW)         // 7340032

__device__ __forceinline__ void atomic_add_f32(float* p, float v) {
#if defined(__gfx90a__) || defined(__gfx940__) || defined(__gfx941__) || defined(__gfx942__) || defined(__gfx950__)
    unsafeAtomicAdd(p, v);   // hardware global_atomic_add_f32
#else
    atomicAdd(p, v);
#endif
}

// One thread per source pixel. Computes flow/weights once, then loops over the
// 64 img channels (coalesced loads within the wave: consecutive lanes are
// consecutive x). 4 atomics per channel + 4 for the norm plane.
__global__ __launch_bounds__(256) void splat_kernel(
    const float* __restrict__ img,
    const float* __restrict__ flow,
    const float* __restrict__ z,
    float* __restrict__ out,      // N*C*H*W accumulator (pre-zeroed)
    float* __restrict__ norm)     // N*H*W accumulator (pre-zeroed)
{
    const int gid = blockIdx.x * 256 + threadIdx.x;   // [0, N*HW)
    const int n = gid / HW;
    const int p = gid - n * HW;
    const int y = p / WW;
    const int x = p - y * WW;

    const float fx = (float)x + flow[(n * 2 + 0) * HW + p];
    const float fy = (float)y + flow[(n * 2 + 1) * HW + p];
    const bool finite = isfinite(fx) && isfinite(fy);
    const float sx = finite ? fx : 0.0f;
    const float sy = finite ? fy : 0.0f;

    const float x0f = floorf(sx);
    const float y0f = floorf(sy);
    const float x1f = x0f + 1.0f;
    const float y1f = y0f + 1.0f;
    const float wx0 = x1f - sx;   // weight toward x0
    const float wx1 = sx - x0f;   // weight toward x1
    const float wy0 = y1f - sy;
    const float wy1 = sy - y0f;

    const int x0 = (int)x0f, y0 = (int)y0f;
    const int x1 = x0 + 1,   y1 = y0 + 1;
    const bool inx0 = (x0 >= 0) & (x0 < WW);
    const bool inx1 = (x1 >= 0) & (x1 < WW);
    const bool iny0 = (y0 >= 0) & (y0 < HH);
    const bool iny1 = (y1 >= 0) & (y1 < HH);

    // mask-folded weights (reference: w * mask, scatter to clipped index)
    const float m00 = (finite & inx0 & iny0) ? 1.0f : 0.0f;
    const float m10 = (finite & inx1 & iny0) ? 1.0f : 0.0f;
    const float m01 = (finite & inx0 & iny1) ? 1.0f : 0.0f;
    const float m11 = (finite & inx1 & iny1) ? 1.0f : 0.0f;

    const float mexp = expf(z[n * HW + p]);

    // fold exp(z) into the weights: w*(img*e) == (w*e)*img
    const float ws00 = wx0 * wy0 * m00 * mexp;
    const float ws10 = wx1 * wy0 * m10 * mexp;
    const float ws01 = wx0 * wy1 * m01 * mexp;
    const float ws11 = wx1 * wy1 * m11 * mexp;

    const int x0c = min(max(x0, 0), WW - 1);
    const int x1c = min(max(x1, 0), WW - 1);
    const int y0c = min(max(y0, 0), HH - 1);
    const int y1c = min(max(y1, 0), HH - 1);

    const int off00 = y0c * WW + x0c;
    const int off10 = y0c * WW + x1c;
    const int off01 = y1c * WW + x0c;
    const int off11 = y1c * WW + x1c;

    // norm plane (prepared channel 64, value = exp(z))
    float* np = norm + n * HW;
    atomic_add_f32(np + off00, ws00);
    atomic_add_f32(np + off10, ws10);
    atomic_add_f32(np + off01, ws01);
    atomic_add_f32(np + off11, ws11);

    const float* imgp = img + (size_t)n * CHW + p;
    float* outp = out + (size_t)n * CHW;
#pragma unroll 4
    for (int c = 0; c < CC; ++c) {
        const float v = imgp[c * HW];
        float* o = outp + c * HW;
        atomic_add_f32(o + off00, ws00 * v);
        atomic_add_f32(o + off10, ws10 * v);
        atomic_add_f32(o + off01, ws01 * v);
        atomic_add_f32(o + off11, ws11 * v);
    }
}

// out[n,c,y,x] /= (norm[n,y,x] == 0 ? 1 : norm[n,y,x]); float4 vectorized.
__global__ __launch_bounds__(256) void norm_kernel(
    float* __restrict__ out, const float* __restrict__ norm)
{
    const int tid = blockIdx.x * 256 + threadIdx.x;   // one float4 each
    const int f = tid * 4;                            // flat float index
    const int n = f / CHW;
    const int r = f - n * CHW;
    const int c = r / HW;
    const int p = r - c * HW;                         // pixel offset, %4==0

    float4 o = *reinterpret_cast<float4*>(out + f);
    const float4 m = *reinterpret_cast<const float4*>(norm + n * HW + p);
    o.x = o.x / (m.x == 0.0f ? 1.0f : m.x);
    o.y = o.y / (m.y == 0.0f ? 1.0f : m.y);
    o.z = o.z / (m.z == 0.0f ? 1.0f : m.z);
    o.w = o.w / (m.w == 0.0f ? 1.0f : m.w);
    *reinterpret_cast<float4*>(out + f) = o;
}

extern "C" void kernel_launch(void* const* d_in, const int* in_sizes, int n_in,
                              void* d_out, int out_size, void* d_ws, size_t ws_size,
                              hipStream_t stream) {
    const float* img  = (const float*)d_in[0];
    const float* flow = (const float*)d_in[1];
    const float* z    = (const float*)d_in[2];
    float* out  = (float*)d_out;
    float* norm = (float*)d_ws;   // N*HW floats = 1.75 MB

    hipMemsetAsync(d_out, 0, (size_t)out_size * sizeof(float), stream);
    hipMemsetAsync(d_ws, 0, (size_t)NN * HW * sizeof(float), stream);

    splat_kernel<<<(NN * HW) / 256, 256, 0, stream>>>(img, flow, z, out, norm);
    norm_kernel<<<(NN * CHW / 4) / 256, 256, 0, stream>>>(out, norm);
}

// Round 2
// 866.142 us; speedup vs baseline: 3.2826x; 3.2826x over previous
//
#include <hip/hip_runtime.h>
#include <cmath>

#define NN 4
#define CC 64
#define HH 256
#define WW 448
#define HW (HH * WW)          // 114688
#define CHW (CC * HW)         // 7340032

#define TW 32                 // output tile width
#define TH 16                 // output tile height
#define TPX (TW * TH)         // 512 px per tile
#define RADI 6                // gather handles |flow| <= RADI; rest via fallback
#define RGW (TW + 2 * RADI + 1)   // 45 source-region cols
#define RGH (TH + 2 * RADI + 1)   // 29 source-region rows
#define RPX (RGW * RGH)       // 1305
#define NTX (WW / TW)         // 14
#define NTY (HH / TH)         // 16
#define CHUNK 16
#define OVCAP 8192

struct __align__(16) OvEntry { int n, p, x0, y0; float w00, w10, w01, w11; };

// Rare path: |flow| > RADI or weird values -> compact global list replayed by
// every gather block. For N(0,1) flow this appends nothing (P ~ 2e-9/px).
__global__ __launch_bounds__(256) void fallback_kernel(
    const float* __restrict__ flow, const float* __restrict__ z, int* __restrict__ ov)
{
    const int gid = blockIdx.x * 256 + threadIdx.x;   // [0, NN*HW)
    const int n = gid / HW;
    const int p = gid - n * HW;
    const int gy = p / WW;
    const int gx = p - gy * WW;
    const float fl0 = flow[(size_t)(n * 2 + 0) * HW + p];
    const float fl1 = flow[(size_t)(n * 2 + 1) * HW + p];
    if (!(isfinite(fl0) && isfinite(fl1))) return;                         // contributes 0
    if (fabsf(fl0) <= (float)RADI && fabsf(fl1) <= (float)RADI) return;    // gather path
    const float sx = (float)gx + fl0, sy = (float)gy + fl1;
    const float x0f = floorf(sx), y0f = floorf(sy);
    const int x0 = (int)x0f, y0 = (int)y0f;
    const float wx1 = sx - x0f, wx0 = 1.0f - wx1;
    const float wy1 = sy - y0f, wy0 = 1.0f - wy1;
    const float me = expf(z[(size_t)n * HW + p]);
    const bool inx0 = (x0 >= 0) & (x0 < WW);
    const bool inx1 = (x0 + 1 >= 0) & (x0 + 1 < WW);
    const bool iny0 = (y0 >= 0) & (y0 < HH);
    const bool iny1 = (y0 + 1 >= 0) & (y0 + 1 < HH);
    OvEntry e;
    e.n = n; e.p = p; e.x0 = x0; e.y0 = y0;
    e.w00 = (inx0 && iny0) ? wx0 * wy0 * me : 0.0f;
    e.w10 = (inx1 && iny0) ? wx1 * wy0 * me : 0.0f;
    e.w01 = (inx0 && iny1) ? wx0 * wy1 * me : 0.0f;
    e.w11 = (inx1 && iny1) ? wx1 * wy1 * me : 0.0f;
    if (e.w00 == 0.0f && e.w10 == 0.0f && e.w01 == 0.0f && e.w11 == 0.0f) return;
    const int idx = atomicAdd(ov, 1);
    if (idx < OVCAP) ((OvEntry*)(ov + 8))[idx] = e;
}

// One block per 32x16 output tile: build contributor list, accumulate 65
// channels in LDS (ds_add_f32), normalize, plain-store the tile. Zero global
// atomics on the hot path.
__global__ __launch_bounds__(256, 2) void gather_kernel(
    const float* __restrict__ img,
    const float* __restrict__ flow,
    const float* __restrict__ z,
    float* __restrict__ out,
    const int* __restrict__ ov)
{
    __shared__ int    s_src[RPX];
    __shared__ int    s_lxy[RPX];
    __shared__ float4 s_w[RPX];
    __shared__ float  s_norm[TPX];
    __shared__ float  s_tile[CHUNK * TPX];
    __shared__ int    s_cnt;

    const int bid = blockIdx.x;
    const int n = bid / (NTX * NTY);
    const int t = bid - n * (NTX * NTY);
    const int tx = (t % NTX) * TW;
    const int ty = (t / NTX) * TH;
    const int tid = threadIdx.x;

    if (tid == 0) s_cnt = 0;
    for (int i = tid; i < TPX; i += 256) s_norm[i] = 0.0f;
    __syncthreads();

    const float* fxp = flow + (size_t)(n * 2 + 0) * HW;
    const float* fyp = flow + (size_t)(n * 2 + 1) * HW;
    const float* zp  = z + (size_t)n * HW;

    // ---- phase 1: scan source region, compact contributor entries ----
    for (int i = tid; i < RPX; i += 256) {
        const int rx = i % RGW, ry = i / RGW;
        const int gx = tx - (RADI + 1) + rx;
        const int gy = ty - (RADI + 1) + ry;
        if (gx < 0 || gx >= WW || gy < 0 || gy >= HH) continue;
        const int p = gy * WW + gx;
        const float fl0 = fxp[p], fl1 = fyp[p];
        if (!(isfinite(fl0) && isfinite(fl1))) continue;
        if (!(fabsf(fl0) <= (float)RADI && fabsf(fl1) <= (float)RADI)) continue; // fallback's
        const float sx = (float)gx + fl0, sy = (float)gy + fl1;
        const float x0f = floorf(sx), y0f = floorf(sy);
        const int x0 = (int)x0f, y0 = (int)y0f;
        // corner set {x0,x0+1}x{y0,y0+1} must intersect this tile
        if (x0 + 1 < tx || x0 > tx + TW - 1 || y0 + 1 < ty || y0 > ty + TH - 1) continue;
        const float wx1 = sx - x0f, wx0 = 1.0f - wx1;
        const float wy1 = sy - y0f, wy0 = 1.0f - wy1;
        const float me = expf(zp[p]);
        const int lx0 = x0 - tx, ly0 = y0 - ty;           // in [-1, TW-1]/[-1, TH-1]
        // tile membership implies image membership (tiles partition the image),
        // so reference's out-of-image mask == "owned by no tile".
        const bool i00 = (lx0 >= 0) & (ly0 >= 0);
        const bool i10 = (lx0 + 1 <= TW - 1) & (ly0 >= 0);
        const bool i01 = (lx0 >= 0) & (ly0 + 1 <= TH - 1);
        const bool i11 = (lx0 + 1 <= TW - 1) & (ly0 + 1 <= TH - 1);
        const float w00 = i00 ? wx0 * wy0 * me : 0.0f;
        const float w10 = i10 ? wx1 * wy0 * me : 0.0f;
        const float w01 = i01 ? wx0 * wy1 * me : 0.0f;
        const float w11 = i11 ? wx1 * wy1 * me : 0.0f;
        if (w00 == 0.0f && w10 == 0.0f && w01 == 0.0f && w11 == 0.0f) continue;
        const int e = atomicAdd(&s_cnt, 1);
        s_src[e] = p;
        s_lxy[e] = (lx0 + 1) | ((ly0 + 1) << 8);
        s_w[e] = make_float4(w00, w10, w01, w11);
        const int b00 = ly0 * TW + lx0;
        if (w00 != 0.0f) atomicAdd(&s_norm[b00], w00);
        if (w10 != 0.0f) atomicAdd(&s_norm[b00 + 1], w10);
        if (w01 != 0.0f) atomicAdd(&s_norm[b00 + TW], w01);
        if (w11 != 0.0f) atomicAdd(&s_norm[b00 + TW + 1], w11);
    }
    __syncthreads();

    // ---- overflow entries: norm contribution (normally zero iterations) ----
    int ovcnt = ov[0];
    ovcnt = ovcnt > OVCAP ? OVCAP : ovcnt;
    const OvEntry* oe = (const OvEntry*)(ov + 8);
    if (ovcnt > 0) {
        for (int i = tid; i < ovcnt; i += 256) {
            OvEntry e = oe[i];
            if (e.n != n) continue;
            const int lx0 = e.x0 - tx, ly0 = e.y0 - ty;
            const int b00 = ly0 * TW + lx0;
            const bool c00 = (lx0 >= 0) & (lx0 < TW) & (ly0 >= 0) & (ly0 < TH) & (e.w00 != 0.0f);
            const bool c10 = (lx0 + 1 >= 0) & (lx0 + 1 < TW) & (ly0 >= 0) & (ly0 < TH) & (e.w10 != 0.0f);
            const bool c01 = (lx0 >= 0) & (lx0 < TW) & (ly0 + 1 >= 0) & (ly0 + 1 < TH) & (e.w01 != 0.0f);
            const bool c11 = (lx0 + 1 >= 0) & (lx0 + 1 < TW) & (ly0 + 1 >= 0) & (ly0 + 1 < TH) & (e.w11 != 0.0f);
            if (c00) atomicAdd(&s_norm[b00], e.w00);
            if (c10) atomicAdd(&s_norm[b00 + 1], e.w10);
            if (c01) atomicAdd(&s_norm[b00 + TW], e.w01);
            if (c11) atomicAdd(&s_norm[b00 + TW + 1], e.w11);
        }
        __syncthreads();
    }

    // finalize: s_norm <- 1/norm (1 if zero)
    for (int i = tid; i < TPX; i += 256) {
        const float v = s_norm[i];
        s_norm[i] = (v == 0.0f) ? 1.0f : 1.0f / v;
    }
    __syncthreads();
    const int nE = s_cnt;

    // ---- phase 2: per 16-channel chunk, accumulate + flush ----
    for (int cb = 0; cb < CC; cb += CHUNK) {
        for (int i = tid; i < CHUNK * TPX; i += 256) s_tile[i] = 0.0f;
        __syncthreads();

        for (int base = 0; base < nE; base += 256) {
            const int e = base + tid;
            if (e < nE) {
                const int p = s_src[e];
                const int lxy = s_lxy[e];
                const int lx0 = (lxy & 255) - 1;
                const int ly0 = (lxy >> 8) - 1;
                const float4 w = s_w[e];
                const int b00 = ly0 * TW + lx0;
                const float* ip = img + (size_t)n * CHW + (size_t)cb * HW + p;
#pragma unroll 4
                for (int c = 0; c < CHUNK; ++c) {
                    const float v = ip[c * HW];
                    float* tp = s_tile + c * TPX;
                    if (w.x != 0.0f) atomicAdd(tp + b00, w.x * v);
                    if (w.y != 0.0f) atomicAdd(tp + b00 + 1, w.y * v);
                    if (w.z != 0.0f) atomicAdd(tp + b00 + TW, w.z * v);
                    if (w.w != 0.0f) atomicAdd(tp + b00 + TW + 1, w.w * v);
                }
            }
        }
        if (ovcnt > 0) {
            for (int i = tid; i < ovcnt; i += 256) {
                OvEntry e = oe[i];
                if (e.n != n) continue;
                const int lx0 = e.x0 - tx, ly0 = e.y0 - ty;
                const int b00 = ly0 * TW + lx0;
                const bool c00 = (lx0 >= 0) & (lx0 < TW) & (ly0 >= 0) & (ly0 < TH) & (e.w00 != 0.0f);
                const bool c10 = (lx0 + 1 >= 0) & (lx0 + 1 < TW) & (ly0 >= 0) & (ly0 < TH) & (e.w10 != 0.0f);
                const bool c01 = (lx0 >= 0) & (lx0 < TW) & (ly0 + 1 >= 0) & (ly0 + 1 < TH) & (e.w01 != 0.0f);
                const bool c11 = (lx0 + 1 >= 0) & (lx0 + 1 < TW) & (ly0 + 1 >= 0) & (ly0 + 1 < TH) & (e.w11 != 0.0f);
                if (!(c00 | c10 | c01 | c11)) continue;
                const float* ip = img + (size_t)e.n * CHW + (size_t)cb * HW + e.p;
                for (int c = 0; c < CHUNK; ++c) {
                    const float v = ip[c * HW];
                    float* tp = s_tile + c * TPX;
                    if (c00) atomicAdd(tp + b00, e.w00 * v);
                    if (c10) atomicAdd(tp + b00 + 1, e.w10 * v);
                    if (c01) atomicAdd(tp + b00 + TW, e.w01 * v);
                    if (c11) atomicAdd(tp + b00 + TW + 1, e.w11 * v);
                }
            }
        }
        __syncthreads();

        // flush tile * rnorm -> out, float4 coalesced (2048 float4 per chunk)
        for (int s = tid; s < CHUNK * (TPX / 4); s += 256) {
            const int c = s / (TPX / 4);
            const int q4 = (s - c * (TPX / 4)) * 4;
            const int lx = q4 % TW, ly = q4 / TW;
            float4 v = *(const float4*)(s_tile + c * TPX + q4);
            const float4 rn = *(const float4*)(s_norm + q4);
            v.x *= rn.x; v.y *= rn.y; v.z *= rn.z; v.w *= rn.w;
            *(float4*)(out + (size_t)n * CHW + (size_t)(cb + c) * HW
                       + (size_t)(ty + ly) * WW + tx + lx) = v;
        }
        __syncthreads();
    }
}

extern "C" void kernel_launch(void* const* d_in, const int* in_sizes, int n_in,
                              void* d_out, int out_size, void* d_ws, size_t ws_size,
                              hipStream_t stream) {
    const float* img  = (const float*)d_in[0];
    const float* flow = (const float*)d_in[1];
    const float* z    = (const float*)d_in[2];
    float* out = (float*)d_out;
    int* ov = (int*)d_ws;   // [0]=count, entries at +32B; needs 32 + OVCAP*32 = 262 KB

    hipMemsetAsync(d_ws, 0, 32, stream);
    fallback_kernel<<<(NN * HW) / 256, 256, 0, stream>>>(flow, z, ov);
    gather_kernel<<<NN * NTX * NTY, 256, 0, stream>>>(img, flow, z, out, ov);
}

// Round 3
// 864.875 us; speedup vs baseline: 3.2874x; 1.0015x over previous
//
#include <hip/hip_runtime.h>
#include <cmath>

#define NN 4
#define CC 64
#define HH 256
#define WW 448
#define HW (HH * WW)          // 114688
#define CHW (CC * HW)         // 7340032

#define TW 32                 // output tile width
#define TH 16                 // output tile height
#define TPX (TW * TH)         // 512 px per tile
#define RADI 6                // gather handles |flow| <= RADI; rest via fallback
#define RGW (TW + 2 * RADI + 1)   // 45 source-region cols
#define RGH (TH + 2 * RADI + 1)   // 29 source-region rows
#define RPX (RGW * RGH)       // 1305
#define NTX (WW / TW)         // 14
#define NTY (HH / TH)         // 16
#define CHUNK 16
#define OVCAP 8192

struct __align__(16) OvEntry { int n, p, x0, y0; float w00, w10, w01, w11; };

// Native ds_add_f32 for LDS accumulators. Plain atomicAdd(float*) on LDS
// lowers to a CAS retry loop (denormal-conservative) -- that was R2's 726us.
__device__ __forceinline__ void lds_add(float* p, float v) {
    unsafeAtomicAdd(p, v);
}

// Rare path: |flow| > RADI or weird values -> compact global list replayed by
// every gather block. For N(0,1) flow this appends nothing (P ~ 2e-9/px).
__global__ __launch_bounds__(256) void fallback_kernel(
    const float* __restrict__ flow, const float* __restrict__ z, int* __restrict__ ov)
{
    const int gid = blockIdx.x * 256 + threadIdx.x;   // [0, NN*HW)
    const int n = gid / HW;
    const int p = gid - n * HW;
    const int gy = p / WW;
    const int gx = p - gy * WW;
    const float fl0 = flow[(size_t)(n * 2 + 0) * HW + p];
    const float fl1 = flow[(size_t)(n * 2 + 1) * HW + p];
    if (!(isfinite(fl0) && isfinite(fl1))) return;                         // contributes 0
    if (fabsf(fl0) <= (float)RADI && fabsf(fl1) <= (float)RADI) return;    // gather path
    const float sx = (float)gx + fl0, sy = (float)gy + fl1;
    const float x0f = floorf(sx), y0f = floorf(sy);
    const int x0 = (int)x0f, y0 = (int)y0f;
    const float wx1 = sx - x0f, wx0 = 1.0f - wx1;
    const float wy1 = sy - y0f, wy0 = 1.0f - wy1;
    const float me = expf(z[(size_t)n * HW + p]);
    const bool inx0 = (x0 >= 0) & (x0 < WW);
    const bool inx1 = (x0 + 1 >= 0) & (x0 + 1 < WW);
    const bool iny0 = (y0 >= 0) & (y0 < HH);
    const bool iny1 = (y0 + 1 >= 0) & (y0 + 1 < HH);
    OvEntry e;
    e.n = n; e.p = p; e.x0 = x0; e.y0 = y0;
    e.w00 = (inx0 && iny0) ? wx0 * wy0 * me : 0.0f;
    e.w10 = (inx1 && iny0) ? wx1 * wy0 * me : 0.0f;
    e.w01 = (inx0 && iny1) ? wx0 * wy1 * me : 0.0f;
    e.w11 = (inx1 && iny1) ? wx1 * wy1 * me : 0.0f;
    if (e.w00 == 0.0f && e.w10 == 0.0f && e.w01 == 0.0f && e.w11 == 0.0f) return;
    const int idx = atomicAdd(ov, 1);
    if (idx < OVCAP) ((OvEntry*)(ov + 8))[idx] = e;
}

// One block per 32x16 output tile: build contributor list, accumulate 65
// channels in LDS (native ds_add_f32), normalize, plain-store the tile.
__global__ __launch_bounds__(256, 2) void gather_kernel(
    const float* __restrict__ img,
    const float* __restrict__ flow,
    const float* __restrict__ z,
    float* __restrict__ out,
    const int* __restrict__ ov)
{
    __shared__ int    s_src[RPX];
    __shared__ int    s_lxy[RPX];
    __shared__ float4 s_w[RPX];
    __shared__ float  s_norm[TPX];
    __shared__ float  s_tile[CHUNK * TPX];
    __shared__ int    s_cnt;

    const int bid = blockIdx.x;
    const int n = bid / (NTX * NTY);
    const int t = bid - n * (NTX * NTY);
    const int tx = (t % NTX) * TW;
    const int ty = (t / NTX) * TH;
    const int tid = threadIdx.x;

    if (tid == 0) s_cnt = 0;
    for (int i = tid; i < TPX; i += 256) s_norm[i] = 0.0f;
    __syncthreads();

    const float* fxp = flow + (size_t)(n * 2 + 0) * HW;
    const float* fyp = flow + (size_t)(n * 2 + 1) * HW;
    const float* zp  = z + (size_t)n * HW;

    // ---- phase 1: scan source region, compact contributor entries ----
    for (int i = tid; i < RPX; i += 256) {
        const int rx = i % RGW, ry = i / RGW;
        const int gx = tx - (RADI + 1) + rx;
        const int gy = ty - (RADI + 1) + ry;
        if (gx < 0 || gx >= WW || gy < 0 || gy >= HH) continue;
        const int p = gy * WW + gx;
        const float fl0 = fxp[p], fl1 = fyp[p];
        if (!(isfinite(fl0) && isfinite(fl1))) continue;
        if (!(fabsf(fl0) <= (float)RADI && fabsf(fl1) <= (float)RADI)) continue; // fallback's
        const float sx = (float)gx + fl0, sy = (float)gy + fl1;
        const float x0f = floorf(sx), y0f = floorf(sy);
        const int x0 = (int)x0f, y0 = (int)y0f;
        // corner set {x0,x0+1}x{y0,y0+1} must intersect this tile
        if (x0 + 1 < tx || x0 > tx + TW - 1 || y0 + 1 < ty || y0 > ty + TH - 1) continue;
        const float wx1 = sx - x0f, wx0 = 1.0f - wx1;
        const float wy1 = sy - y0f, wy0 = 1.0f - wy1;
        const float me = expf(zp[p]);
        const int lx0 = x0 - tx, ly0 = y0 - ty;           // in [-1, TW-1]/[-1, TH-1]
        // tile membership implies image membership (tiles partition the image),
        // so reference's out-of-image mask == "owned by no tile".
        const bool i00 = (lx0 >= 0) & (ly0 >= 0);
        const bool i10 = (lx0 + 1 <= TW - 1) & (ly0 >= 0);
        const bool i01 = (lx0 >= 0) & (ly0 + 1 <= TH - 1);
        const bool i11 = (lx0 + 1 <= TW - 1) & (ly0 + 1 <= TH - 1);
        const float w00 = i00 ? wx0 * wy0 * me : 0.0f;
        const float w10 = i10 ? wx1 * wy0 * me : 0.0f;
        const float w01 = i01 ? wx0 * wy1 * me : 0.0f;
        const float w11 = i11 ? wx1 * wy1 * me : 0.0f;
        if (w00 == 0.0f && w10 == 0.0f && w01 == 0.0f && w11 == 0.0f) continue;
        const int e = atomicAdd(&s_cnt, 1);
        s_src[e] = p;
        s_lxy[e] = (lx0 + 1) | ((ly0 + 1) << 8);
        s_w[e] = make_float4(w00, w10, w01, w11);
        const int b00 = ly0 * TW + lx0;
        if (w00 != 0.0f) lds_add(&s_norm[b00], w00);
        if (w10 != 0.0f) lds_add(&s_norm[b00 + 1], w10);
        if (w01 != 0.0f) lds_add(&s_norm[b00 + TW], w01);
        if (w11 != 0.0f) lds_add(&s_norm[b00 + TW + 1], w11);
    }
    __syncthreads();

    // ---- overflow entries: norm contribution (normally zero iterations) ----
    int ovcnt = ov[0];
    ovcnt = ovcnt > OVCAP ? OVCAP : ovcnt;
    const OvEntry* oe = (const OvEntry*)(ov + 8);
    if (ovcnt > 0) {
        for (int i = tid; i < ovcnt; i += 256) {
            OvEntry e = oe[i];
            if (e.n != n) continue;
            const int lx0 = e.x0 - tx, ly0 = e.y0 - ty;
            const int b00 = ly0 * TW + lx0;
            const bool c00 = (lx0 >= 0) & (lx0 < TW) & (ly0 >= 0) & (ly0 < TH) & (e.w00 != 0.0f);
            const bool c10 = (lx0 + 1 >= 0) & (lx0 + 1 < TW) & (ly0 >= 0) & (ly0 < TH) & (e.w10 != 0.0f);
            const bool c01 = (lx0 >= 0) & (lx0 < TW) & (ly0 + 1 >= 0) & (ly0 + 1 < TH) & (e.w01 != 0.0f);
            const bool c11 = (lx0 + 1 >= 0) & (lx0 + 1 < TW) & (ly0 + 1 >= 0) & (ly0 + 1 < TH) & (e.w11 != 0.0f);
            if (c00) lds_add(&s_norm[b00], e.w00);
            if (c10) lds_add(&s_norm[b00 + 1], e.w10);
            if (c01) lds_add(&s_norm[b00 + TW], e.w01);
            if (c11) lds_add(&s_norm[b00 + TW + 1], e.w11);
        }
        __syncthreads();
    }

    // finalize: s_norm <- 1/norm (1 if zero)
    for (int i = tid; i < TPX; i += 256) {
        const float v = s_norm[i];
        s_norm[i] = (v == 0.0f) ? 1.0f : 1.0f / v;
    }
    __syncthreads();
    const int nE = s_cnt;

    // ---- phase 2: per 16-channel chunk, accumulate + flush ----
    for (int cb = 0; cb < CC; cb += CHUNK) {
        for (int i = tid; i < CHUNK * TPX; i += 256) s_tile[i] = 0.0f;
        __syncthreads();

        for (int base = 0; base < nE; base += 256) {
            const int e = base + tid;
            if (e < nE) {
                const int p = s_src[e];
                const int lxy = s_lxy[e];
                const int lx0 = (lxy & 255) - 1;
                const int ly0 = (lxy >> 8) - 1;
                const float4 w = s_w[e];
                const int b00 = ly0 * TW + lx0;
                const float* ip = img + (size_t)n * CHW + (size_t)cb * HW + p;
                // preload all CHUNK channel values -> 16 outstanding loads
                float v[CHUNK];
#pragma unroll
                for (int c = 0; c < CHUNK; ++c) v[c] = ip[c * HW];
#pragma unroll
                for (int c = 0; c < CHUNK; ++c) {
                    float* tp = s_tile + c * TPX;
                    if (w.x != 0.0f) lds_add(tp + b00, w.x * v[c]);
                    if (w.y != 0.0f) lds_add(tp + b00 + 1, w.y * v[c]);
                    if (w.z != 0.0f) lds_add(tp + b00 + TW, w.z * v[c]);
                    if (w.w != 0.0f) lds_add(tp + b00 + TW + 1, w.w * v[c]);
                }
            }
        }
        if (ovcnt > 0) {
            for (int i = tid; i < ovcnt; i += 256) {
                OvEntry e = oe[i];
                if (e.n != n) continue;
                const int lx0 = e.x0 - tx, ly0 = e.y0 - ty;
                const int b00 = ly0 * TW + lx0;
                const bool c00 = (lx0 >= 0) & (lx0 < TW) & (ly0 >= 0) & (ly0 < TH) & (e.w00 != 0.0f);
                const bool c10 = (lx0 + 1 >= 0) & (lx0 + 1 < TW) & (ly0 >= 0) & (ly0 < TH) & (e.w10 != 0.0f);
                const bool c01 = (lx0 >= 0) & (lx0 < TW) & (ly0 + 1 >= 0) & (ly0 + 1 < TH) & (e.w01 != 0.0f);
                const bool c11 = (lx0 + 1 >= 0) & (lx0 + 1 < TW) & (ly0 + 1 >= 0) & (ly0 + 1 < TH) & (e.w11 != 0.0f);
                if (!(c00 | c10 | c01 | c11)) continue;
                const float* ip = img + (size_t)e.n * CHW + (size_t)cb * HW + e.p;
                for (int c = 0; c < CHUNK; ++c) {
                    const float v = ip[c * HW];
                    float* tp = s_tile + c * TPX;
                    if (c00) lds_add(tp + b00, e.w00 * v);
                    if (c10) lds_add(tp + b00 + 1, e.w10 * v);
                    if (c01) lds_add(tp + b00 + TW, e.w01 * v);
                    if (c11) lds_add(tp + b00 + TW + 1, e.w11 * v);
                }
            }
        }
        __syncthreads();

        // flush tile * rnorm -> out, float4 coalesced (2048 float4 per chunk)
        for (int s = tid; s < CHUNK * (TPX / 4); s += 256) {
            const int c = s / (TPX / 4);
            const int q4 = (s - c * (TPX / 4)) * 4;
            const int lx = q4 % TW, ly = q4 / TW;
            float4 v = *(const float4*)(s_tile + c * TPX + q4);
            const float4 rn = *(const float4*)(s_norm + q4);
            v.x *= rn.x; v.y *= rn.y; v.z *= rn.z; v.w *= rn.w;
            *(float4*)(out + (size_t)n * CHW + (size_t)(cb + c) * HW
                       + (size_t)(ty + ly) * WW + tx + lx) = v;
        }
        __syncthreads();
    }
}

extern "C" void kernel_launch(void* const* d_in, const int* in_sizes, int n_in,
                              void* d_out, int out_size, void* d_ws, size_t ws_size,
                              hipStream_t stream) {
    const float* img  = (const float*)d_in[0];
    const float* flow = (const float*)d_in[1];
    const float* z    = (const float*)d_in[2];
    float* out = (float*)d_out;
    int* ov = (int*)d_ws;   // [0]=count, entries at +32B; needs 32 + OVCAP*32 = 262 KB

    hipMemsetAsync(d_ws, 0, 32, stream);
    fallback_kernel<<<(NN * HW) / 256, 256, 0, stream>>>(flow, z, ov);
    gather_kernel<<<NN * NTX * NTY, 256, 0, stream>>>(img, flow, z, out, ov);
}